// Round 12
// baseline (627.462 us; speedup 1.0000x reference)
//
#include <hip/hip_runtime.h>

// ---------------- workspace layout (float offsets) ----------------
constexpr int L0 = 2048;
constexpr size_t OFF_POOLED = 0;                  // 1024*8
constexpr size_t OFF_TOPKI  = 8192;               // 2048 ints
constexpr size_t OFF_TOPKG  = 10240;              // 2048 floats
constexpr size_t OFF_B1     = 12288;              // 64
constexpr size_t OFF_B2     = 12352;              // 128
constexpr size_t OFF_B3     = 12480;              // 256
constexpr size_t OFF_W1Q    = 12800;              // 2048  [e][cp8][ci8][8]
constexpr size_t OFF_W2Q    = 14848;              // 8192  [e][cp16][ci16][8]
constexpr size_t OFF_W3Q    = 23040;              // 32768 [e][cp32][ci32][8]
constexpr size_t OFF_COMB   = 57344;              // 1024*16384  tile-major [b][t8][co64][j32]
constexpr size_t OFF_P      = 57344 + 16777216;   // 16*1024*64

// ---------------- pooling kernel: pooled[b,c] = mean_l relu(conv1(x)) ----------------
__global__ __launch_bounds__(256) void pool_kernel(const float* __restrict__ x,
    const float* __restrict__ c1w, const float* __restrict__ c1b, float* __restrict__ pooled)
{
    __shared__ float xbuf[2050];
    __shared__ float part[4][8];
    int b = blockIdx.x, tid = threadIdx.x;
    const float* xr = x + (size_t)b * L0;
    for (int i = tid; i < 2050; i += 256) xbuf[i] = (i >= 1 && i <= L0) ? xr[i - 1] : 0.f;
    __syncthreads();
    float w[24], bb[8];
#pragma unroll
    for (int i = 0; i < 24; i++) w[i] = c1w[i];
#pragma unroll
    for (int c = 0; c < 8; c++) bb[c] = c1b[c];
    float acc[8];
#pragma unroll
    for (int c = 0; c < 8; c++) acc[c] = 0.f;
    for (int l = tid; l < L0; l += 256) {
        float xm = xbuf[l], x0 = xbuf[l + 1], xp = xbuf[l + 2];
#pragma unroll
        for (int c = 0; c < 8; c++)
            acc[c] += fmaxf(fmaf(w[3 * c], xm, fmaf(w[3 * c + 1], x0, fmaf(w[3 * c + 2], xp, bb[c]))), 0.f);
    }
#pragma unroll
    for (int c = 0; c < 8; c++) {
#pragma unroll
        for (int off = 32; off > 0; off >>= 1)
            acc[c] += __shfl_down(acc[c], off, 64);
    }
    int wv = tid >> 6, ln = tid & 63;
    if (ln == 0) {
#pragma unroll
        for (int c = 0; c < 8; c++) part[wv][c] = acc[c];
    }
    __syncthreads();
    if (tid < 8) {
        float s = part[0][tid] + part[1][tid] + part[2][tid] + part[3][tid];
        pooled[b * 8 + tid] = s * (1.f / L0);
    }
}

// ---------------- weight repack + BN fold: wq[e][cp][ci][2][4] ----------------
__global__ __launch_bounds__(256) void repack_kernel(
    const float* __restrict__ ew1, const float* __restrict__ eb1, const float* __restrict__ g1,
    const float* __restrict__ bb1, const float* __restrict__ m1, const float* __restrict__ v1,
    const float* __restrict__ ew2, const float* __restrict__ eb2, const float* __restrict__ g2,
    const float* __restrict__ bb2, const float* __restrict__ m2, const float* __restrict__ v2,
    const float* __restrict__ ew3, const float* __restrict__ eb3, const float* __restrict__ g3,
    const float* __restrict__ bb3, const float* __restrict__ m3, const float* __restrict__ v3,
    float* __restrict__ w1q, float* __restrict__ w2q, float* __restrict__ w3q,
    float* __restrict__ b1p, float* __restrict__ b2p, float* __restrict__ b3p)
{
    int i = blockIdx.x * 256 + threadIdx.x;
    if (i < 2048) {
        int k = i & 3, c = (i >> 2) & 1, ci = (i >> 3) & 7, cp = (i >> 6) & 7, e = i >> 9;
        int ec = e * 16 + 2 * cp + c;
        float A = g1[ec] * rsqrtf(v1[ec] + 1e-5f);
        w1q[i] = (k < 3) ? ew1[(ec * 8 + ci) * 3 + k] * A : 0.f;
    } else if (i < 10240) {
        int ii = i - 2048;
        int k = ii & 3, c = (ii >> 2) & 1, ci = (ii >> 3) & 15, cp = (ii >> 7) & 15, e = ii >> 11;
        int ec = e * 32 + 2 * cp + c;
        float A = g2[ec] * rsqrtf(v2[ec] + 1e-5f);
        w2q[ii] = (k < 3) ? ew2[(ec * 16 + ci) * 3 + k] * A : 0.f;
    } else if (i < 43008) {
        int ii = i - 10240;
        int k = ii & 3, c = (ii >> 2) & 1, ci = (ii >> 3) & 31, cp = (ii >> 8) & 31, e = ii >> 13;
        int ec = e * 64 + 2 * cp + c;
        float A = g3[ec] * rsqrtf(v3[ec] + 1e-5f);
        w3q[ii] = (k < 3) ? ew3[(ec * 32 + ci) * 3 + k] * A : 0.f;
    } else if (i < 43456) {
        int j = i - 43008;
        if (j < 64)       { float A = g1[j] * rsqrtf(v1[j] + 1e-5f); b1p[j] = fmaf(eb1[j] - m1[j], A, bb1[j]); }
        else if (j < 192) { int q = j - 64;  float A = g2[q] * rsqrtf(v2[q] + 1e-5f); b2p[q] = fmaf(eb2[q] - m2[q], A, bb2[q]); }
        else              { int q = j - 192; float A = g3[q] * rsqrtf(v3[q] + 1e-5f); b3p[q] = fmaf(eb3[q] - m3[q], A, bb3[q]); }
    }
}

// ---------------- router: softmax, top-2, gates, aux loss ----------------
__global__ __launch_bounds__(1024) void router_kernel(const float* __restrict__ pooled,
    const float* __restrict__ rw, const float* __restrict__ rb,
    int* __restrict__ tidx, float* __restrict__ tg, float* __restrict__ aux)
{
    __shared__ float pr[4][1024];
    int b = threadIdx.x;
    float p[8];
#pragma unroll
    for (int c = 0; c < 8; c++) p[c] = pooled[b * 8 + c];
    float lg[4];
#pragma unroll
    for (int e = 0; e < 4; e++) {
        float a = rb[e];
#pragma unroll
        for (int c = 0; c < 8; c++) a = fmaf(p[c], rw[e * 8 + c], a);
        lg[e] = a;
    }
    float m = fmaxf(fmaxf(lg[0], lg[1]), fmaxf(lg[2], lg[3]));
    float pe[4]; float s = 0.f;
#pragma unroll
    for (int e = 0; e < 4; e++) { pe[e] = expf(lg[e] - m); s += pe[e]; }
    float inv = 1.f / s;
#pragma unroll
    for (int e = 0; e < 4; e++) pe[e] *= inv;
    int e0 = 0;
#pragma unroll
    for (int e = 1; e < 4; e++) if (pe[e] > pe[e0]) e0 = e;
    int e1 = -1;
#pragma unroll
    for (int e = 0; e < 4; e++) if (e != e0 && (e1 < 0 || pe[e] > pe[e1])) e1 = e;
    float s2 = pe[e0] + pe[e1];
    tidx[b * 2] = e0; tidx[b * 2 + 1] = e1;
    tg[b * 2] = pe[e0] / s2; tg[b * 2 + 1] = pe[e1] / s2;
#pragma unroll
    for (int e = 0; e < 4; e++) pr[e][b] = pe[e];
    __syncthreads();
    for (int off = 512; off > 0; off >>= 1) {
        if (b < off) {
#pragma unroll
            for (int e = 0; e < 4; e++) pr[e][b] += pr[e][b + off];
        }
        __syncthreads();
    }
    if (b == 0) {
        float mp[4]; float mm = 0.f;
#pragma unroll
        for (int e = 0; e < 4; e++) { mp[e] = pr[e][0] * (1.f / 1024.f); mm += mp[e]; }
        mm *= 0.25f;
        float var = 0.f;
#pragma unroll
        for (int e = 0; e < 4; e++) { float d = mp[e] - mm; var += d * d; }
        var *= (1.f / 3.f);
        float cv = sqrtf(var) / (mm + 1e-10f);
        aux[0] = cv * cv;
    }
}

// ---------------- expert chain, T=32 final positions per block ----------------
// LDS with lifetime aliasing (B0 recomputed per slot; B0 and S2 share a region):
constexpr int XB_OFF = 0;      // 288
constexpr int E1_OFF = 288;    // 16 x 76
constexpr int O1_OFF = 1504;   // 16 x 76
constexpr int E0_OFF = 2720;   // 8 x 148  (aliases E2)
constexpr int O0_OFF = 3904;   // 8 x 148
constexpr int E2_OFF = 2720;   // 32 x 36
constexpr int O2_OFF = 3872;   // 32 x 36 -> ends 5024
constexpr int LDS_FLOATS = 5088;   // 20352 B

#define DO_C(c, W) \
    aE[c][0] = fmaf(W.x, ev.x, fmaf(W.y, ov.x, fmaf(W.z, ev.y, aE[c][0]))); \
    aO[c][0] = fmaf(W.x, ov.x, fmaf(W.y, ev.y, fmaf(W.z, ov.y, aO[c][0]))); \
    aE[c][1] = fmaf(W.x, ev.y, fmaf(W.y, ov.y, fmaf(W.z, ev.z, aE[c][1]))); \
    aO[c][1] = fmaf(W.x, ov.y, fmaf(W.y, ev.z, fmaf(W.z, ov.z, aO[c][1]))); \
    aE[c][2] = fmaf(W.x, ev.z, fmaf(W.y, ov.z, fmaf(W.z, ev.w, aE[c][2]))); \
    aO[c][2] = fmaf(W.x, ov.z, fmaf(W.y, ev.w, fmaf(W.z, ov.w, aO[c][2]))); \
    aE[c][3] = fmaf(W.x, ev.w, fmaf(W.y, ov.w, fmaf(W.z, e4, aE[c][3]))); \
    aO[c][3] = fmaf(W.x, ov.w, fmaf(W.y, e4, fmaf(W.z, o4, aO[c][3])));

// 2 output channels x 4 positions; weights per-thread contiguous [CI][8]
// R4-proven register shape + R4-proven '#pragma unroll 4' (full unroll spills: R9)
template<int CI, int SIN, int SOUT, int LOUT, bool GUARDJ>
__device__ __forceinline__ void stage2x4(
    const float* __restrict__ wq, const float b0, const float b1,
    const float* __restrict__ Ein, const float* __restrict__ Oin,
    float* __restrict__ Eout, float* __restrict__ Oout,
    const int co0, const int j0, const int a_out, const int jmax)
{
    float aE[2][4], aO[2][4];
#pragma unroll
    for (int p = 0; p < 4; ++p) { aE[0][p] = b0; aO[0][p] = b0; aE[1][p] = b1; aO[1][p] = b1; }
#pragma unroll 4
    for (int ci = 0; ci < CI; ++ci) {
        const float4 wA = *reinterpret_cast<const float4*>(wq + ci * 8);
        const float4 wB = *reinterpret_cast<const float4*>(wq + ci * 8 + 4);
        const float* ep = Ein + ci * SIN + j0;
        const float4 ev = *reinterpret_cast<const float4*>(ep);
        const float e4 = ep[4];
        const float* op = Oin + ci * SIN + j0;
        const float4 ov = *reinterpret_cast<const float4*>(op);
        const float o4 = op[4];
        DO_C(0, wA) DO_C(1, wB)
    }
#pragma unroll
    for (int c = 0; c < 2; ++c) {
        float v[4];
#pragma unroll
        for (int p = 0; p < 4; ++p) {
            int l = a_out + j0 + p;
            bool ok = (l >= 0) && (l < LOUT);
            if (GUARDJ) ok = ok && (j0 + p < jmax);
            v[p] = ok ? fmaxf(fmaxf(aE[c][p], aO[c][p]), 0.f) : 0.f;
        }
        *reinterpret_cast<float2*>(Eout + (co0 + c) * SOUT + (j0 >> 1)) = make_float2(v[0], v[2]);
        *reinterpret_cast<float2*>(Oout + (co0 + c) * SOUT + (j0 >> 1)) = make_float2(v[1], v[3]);
    }
}

// stage3: 2ch x 4pos, gated accumulate into registers
__device__ __forceinline__ void stage3_2x4(
    const float* __restrict__ wq, const float b0, const float b1,
    const float* __restrict__ Ein, const float* __restrict__ Oin,
    const float g, float oa[2][4], const int j0)
{
    float aE[2][4], aO[2][4];
#pragma unroll
    for (int p = 0; p < 4; ++p) { aE[0][p] = b0; aO[0][p] = b0; aE[1][p] = b1; aO[1][p] = b1; }
#pragma unroll 4
    for (int ci = 0; ci < 32; ++ci) {
        const float4 wA = *reinterpret_cast<const float4*>(wq + ci * 8);
        const float4 wB = *reinterpret_cast<const float4*>(wq + ci * 8 + 4);
        const float* ep = Ein + ci * 36 + j0;
        const float4 ev = *reinterpret_cast<const float4*>(ep);
        const float e4 = ep[4];
        const float* op = Oin + ci * 36 + j0;
        const float4 ov = *reinterpret_cast<const float4*>(op);
        const float o4 = op[4];
        DO_C(0, wA) DO_C(1, wB)
    }
#pragma unroll
    for (int c = 0; c < 2; ++c)
#pragma unroll
        for (int p = 0; p < 4; ++p)
            oa[c][p] = fmaf(g, fmaxf(fmaxf(aE[c][p], aO[c][p]), 0.f), oa[c][p]);
}

__global__ __launch_bounds__(256) void expert_kernel(
    const float* __restrict__ x, const float* __restrict__ c1w, const float* __restrict__ c1b,
    const float* __restrict__ w1q, const float* __restrict__ w2q, const float* __restrict__ w3q,
    const float* __restrict__ b1p, const float* __restrict__ b2p, const float* __restrict__ b3p,
    const int* __restrict__ tidx, const float* __restrict__ tg,
    float* __restrict__ comb)
{
    __shared__ __align__(16) float lds[LDS_FLOATS];
    const int tid = threadIdx.x;
    const int bt = blockIdx.x;
    const int b = bt >> 3, t = bt & 7;
    const int a3 = t * 32, a2 = 2 * a3 - 1, a1 = 4 * a3 - 3, a0 = 8 * a3 - 7;
    const float* xr = x + (size_t)b * L0;
    float* xb = lds + XB_OFF;
    for (int m = tid; m < 284; m += 256) {
        int gpos = a0 - 1 + m;
        xb[m] = (gpos >= 0 && gpos < L0) ? xr[gpos] : 0.f;
    }
    const int ea = tidx[b * 2], eb2i = tidx[b * 2 + 1];
    const float ga = tg[b * 2], gb2 = tg[b * 2 + 1];
    // thread maps (tails confined to wave 0)
    const int cp1 = tid & 7,  pg1 = tid >> 3;   // stage1: 8 ch-pairs x 32 pos-groups(4)
    const int cp2 = tid & 15, pg2 = tid >> 4;   // stage2: 16 ch-pairs x 16 pos-groups(4)
    const int cp3 = tid >> 3, pg3 = tid & 7;    // stage3: 32 ch-pairs x 8 pos-groups(4)
    const int j3 = 4 * pg3;
    float oa[2][4];
#pragma unroll
    for (int c = 0; c < 2; c++)
#pragma unroll
        for (int p = 0; p < 4; p++) oa[c][p] = 0.f;
#pragma unroll 1
    for (int slot = 0; slot < 2; ++slot) {
        const int e = slot ? eb2i : ea;
        const float g = slot ? gb2 : ga;
        __syncthreads();   // xb ready (slot0) / prev-slot stage3 done reading S2 (=B0 region)
        // stage0: conv1+relu -> E0/O0 (8 x 148), rel j in [0, 282)  [recomputed per slot]
        {
            const int ch = tid & 7;
            const int pj = tid >> 3;
            float wa = c1w[ch * 3], wb = c1w[ch * 3 + 1], wc = c1w[ch * 3 + 2], bc = c1b[ch];
            float* tgt = lds + ((pj & 1) ? O0_OFF : E0_OFF) + ch * 148;
            const int kb = pj >> 1;
            for (int k = 0; k < 9; ++k) {
                int j = pj + 32 * k;
                if (j >= 282) break;
                int l = a0 + j;
                float v = 0.f;
                if (l >= 0 && l < L0)
                    v = fmaxf(fmaf(wa, xb[j], fmaf(wb, xb[j + 1], fmaf(wc, xb[j + 2], bc))), 0.f);
                tgt[kb + 16 * k] = v;
            }
        }
        __syncthreads();   // B0 ready; prev-slot stage2 done reading S1
        // stage1: CI=8 CO=16, JOUT=138
        {
            const float* wq = w1q + (size_t)(e * 8 + cp1) * 64;
            const float2 bb = *reinterpret_cast<const float2*>(b1p + e * 16 + 2 * cp1);
            stage2x4<8, 148, 76, 1024, false>(wq, bb.x, bb.y, lds + E0_OFF, lds + O0_OFF,
                                              lds + E1_OFF, lds + O1_OFF, 2 * cp1, 4 * pg1, a1, 0);
            if (pg1 < 3)
                stage2x4<8, 148, 76, 1024, true>(wq, bb.x, bb.y, lds + E0_OFF, lds + O0_OFF,
                                                 lds + E1_OFF, lds + O1_OFF, 2 * cp1, 128 + 4 * pg1, a1, 138);
        }
        __syncthreads();   // S1 ready; stage1 done reading B0 (S2 may overwrite)
        // stage2: CI=16 CO=32, JOUT=66
        {
            const float* wq = w2q + (size_t)(e * 16 + cp2) * 128;
            const float2 bb = *reinterpret_cast<const float2*>(b2p + e * 32 + 2 * cp2);
            stage2x4<16, 76, 36, 512, false>(wq, bb.x, bb.y, lds + E1_OFF, lds + O1_OFF,
                                             lds + E2_OFF, lds + O2_OFF, 2 * cp2, 4 * pg2, a2, 0);
            if (pg2 == 0)
                stage2x4<16, 76, 36, 512, true>(wq, bb.x, bb.y, lds + E1_OFF, lds + O1_OFF,
                                                lds + E2_OFF, lds + O2_OFF, 2 * cp2, 64, a2, 66);
        }
        __syncthreads();   // S2 ready
        // stage3: CI=32 CO=64, JOUT=32 exact; gated accumulate in regs
        {
            const float* wq = w3q + (size_t)(e * 32 + cp3) * 256;
            const float2 bb = *reinterpret_cast<const float2*>(b3p + e * 64 + 2 * cp3);
            stage3_2x4(wq, bb.x, bb.y, lds + E2_OFF, lds + O2_OFF, g, oa, j3);
        }
    }
    // tile-major comb: comb[b][t][co][j], block writes contiguous 8KB
    float* cb = comb + (size_t)b * 16384 + (size_t)t * 2048 + (2 * cp3) * 32 + j3;
    *reinterpret_cast<float4*>(cb)      = make_float4(oa[0][0], oa[0][1], oa[0][2], oa[0][3]);
    *reinterpret_cast<float4*>(cb + 32) = make_float4(oa[1][0], oa[1][1], oa[1][2], oa[1][3]);
}

// ---------------- fc1 split-K GEMM on tile-major comb: P[kc][b][64] ----------------
__global__ __launch_bounds__(256) void fc1_kernel(const float* __restrict__ comb,
    const float* __restrict__ w, float* __restrict__ P)
{
    __shared__ __align__(16) float at[64 * 65];
    __shared__ __align__(16) float wt[64 * 65];
    int bc = blockIdx.x;   // 0..15 row chunk
    int kc = blockIdx.y;   // 0..15 k chunk
    int tid = threadIdx.x;
    int tx = tid & 15, ty = tid >> 4;
    float acc[4][4];
#pragma unroll
    for (int i = 0; i < 4; i++)
#pragma unroll
        for (int j = 0; j < 4; j++) acc[i][j] = 0.f;
    int b0 = bc * 64;
    for (int kt = 0; kt < 16; ++kt) {
        int k0 = kc * 1024 + kt * 64;
        int co = k0 >> 8;        // flat k = co*256 + l, l = t*32 + j
        int l0 = k0 & 255;
        __syncthreads();
        for (int i = tid; i < 4096; i += 256) {
            int r = i >> 6, kk = i & 63;
            int l = l0 + kk;
            at[r * 65 + kk] = comb[(size_t)(b0 + r) * 16384 + ((l >> 5) << 11) + co * 32 + (l & 31)];
            wt[r * 65 + kk] = w[(size_t)r * 16384 + k0 + kk];
        }
        __syncthreads();
#pragma unroll 8
        for (int kk = 0; kk < 64; kk++) {
            float av[4], wv[4];
#pragma unroll
            for (int i = 0; i < 4; i++) av[i] = at[(ty * 4 + i) * 65 + kk];
#pragma unroll
            for (int j = 0; j < 4; j++) wv[j] = wt[(tx * 4 + j) * 65 + kk];
#pragma unroll
            for (int i = 0; i < 4; i++)
#pragma unroll
                for (int j = 0; j < 4; j++) acc[i][j] = fmaf(av[i], wv[j], acc[i][j]);
        }
    }
    float* Pp = P + (size_t)kc * 65536;
#pragma unroll
    for (int i = 0; i < 4; i++)
#pragma unroll
        for (int j = 0; j < 4; j++)
            Pp[(size_t)(b0 + ty * 4 + i) * 64 + tx * 4 + j] = acc[i][j];
}

// ---------------- reduce partials + bias + relu + fc2 ----------------
__global__ __launch_bounds__(64) void fc2_kernel(const float* __restrict__ P,
    const float* __restrict__ f1b, const float* __restrict__ w2, const float* __restrict__ b2,
    float* __restrict__ out)
{
    int b = blockIdx.x * 64 + threadIdx.x;  // 0..1023
    float z[64];
#pragma unroll
    for (int n = 0; n < 64; n++) z[n] = 0.f;
    for (int kc = 0; kc < 16; kc++) {
        const float* Pp = P + (size_t)kc * 65536 + (size_t)b * 64;
#pragma unroll
        for (int n = 0; n < 64; n++) z[n] += Pp[n];
    }
    float o[5] = {0.f, 0.f, 0.f, 0.f, 0.f};
#pragma unroll
    for (int n = 0; n < 64; n++) {
        float zz = fmaxf(z[n] + f1b[n], 0.f);
#pragma unroll
        for (int c = 0; c < 5; c++) o[c] = fmaf(zz, w2[c * 64 + n], o[c]);
    }
#pragma unroll
    for (int c = 0; c < 5; c++) out[b * 5 + c] = o[c] + b2[c];
}

extern "C" void kernel_launch(void* const* d_in, const int* in_sizes, int n_in,
                              void* d_out, int out_size, void* d_ws, size_t ws_size,
                              hipStream_t stream)
{
    const float* x   = (const float*)d_in[0];
    const float* c1w = (const float*)d_in[1];
    const float* c1b = (const float*)d_in[2];
    const float* ew1 = (const float*)d_in[3];
    const float* eb1 = (const float*)d_in[4];
    const float* g1  = (const float*)d_in[5];
    const float* bb1 = (const float*)d_in[6];
    const float* m1  = (const float*)d_in[7];
    const float* v1  = (const float*)d_in[8];
    const float* ew2 = (const float*)d_in[9];
    const float* eb2 = (const float*)d_in[10];
    const float* g2  = (const float*)d_in[11];
    const float* bb2 = (const float*)d_in[12];
    const float* m2  = (const float*)d_in[13];
    const float* v2  = (const float*)d_in[14];
    const float* ew3 = (const float*)d_in[15];
    const float* eb3 = (const float*)d_in[16];
    const float* g3  = (const float*)d_in[17];
    const float* bb3 = (const float*)d_in[18];
    const float* m3  = (const float*)d_in[19];
    const float* v3  = (const float*)d_in[20];
    const float* rw  = (const float*)d_in[21];
    const float* rb  = (const float*)d_in[22];
    const float* f1w = (const float*)d_in[23];
    const float* f1b = (const float*)d_in[24];
    const float* f2w = (const float*)d_in[25];
    const float* f2b = (const float*)d_in[26];

    float* ws     = (float*)d_ws;
    float* pooled = ws + OFF_POOLED;
    int*   tidx   = (int*)(ws + OFF_TOPKI);
    float* tg     = ws + OFF_TOPKG;
    float* b1p    = ws + OFF_B1;
    float* b2p    = ws + OFF_B2;
    float* b3p    = ws + OFF_B3;
    float* w1q    = ws + OFF_W1Q;
    float* w2q    = ws + OFF_W2Q;
    float* w3q    = ws + OFF_W3Q;
    float* comb   = ws + OFF_COMB;
    float* P      = ws + OFF_P;
    float* out    = (float*)d_out;

    hipLaunchKernelGGL(pool_kernel, dim3(1024), dim3(256), 0, stream, x, c1w, c1b, pooled);
    hipLaunchKernelGGL(repack_kernel, dim3(170), dim3(256), 0, stream,
                       ew1, eb1, g1, bb1, m1, v1, ew2, eb2, g2, bb2, m2, v2,
                       ew3, eb3, g3, bb3, m3, v3, w1q, w2q, w3q, b1p, b2p, b3p);
    hipLaunchKernelGGL(router_kernel, dim3(1), dim3(1024), 0, stream, pooled, rw, rb, tidx, tg, out + 5120);
    hipLaunchKernelGGL(expert_kernel, dim3(8192), dim3(256), 0, stream,
                       x, c1w, c1b, w1q, w2q, w3q, b1p, b2p, b3p, tidx, tg, comb);
    hipLaunchKernelGGL(fc1_kernel, dim3(16, 16), dim3(256), 0, stream, comb, f1w, P);
    hipLaunchKernelGGL(fc2_kernel, dim3(16), dim3(64), 0, stream, P, f1b, f2w, f2b, out);
}

// Round 13
// 409.338 us; speedup vs baseline: 1.5329x; 1.5329x over previous
//
#include <hip/hip_runtime.h>

// ---------------- workspace layout (float offsets) ----------------
constexpr int L0 = 2048;
constexpr size_t OFF_POOLED = 0;                  // 1024*8
constexpr size_t OFF_TOPKI  = 8192;               // 2048 ints
constexpr size_t OFF_TOPKG  = 10240;              // 2048 floats
constexpr size_t OFF_B1     = 12288;              // 64
constexpr size_t OFF_B2     = 12352;              // 128
constexpr size_t OFF_B3     = 12480;              // 256
constexpr size_t OFF_W1Q    = 12800;              // 2048  [e][co16][ci8][4]
constexpr size_t OFF_W2Q    = 14848;              // 8192  [e][co32][ci16][4]
constexpr size_t OFF_W3Q    = 23040;              // 32768 [e][co64][ci32][4]
constexpr size_t OFF_COMB   = 57344;              // 1024*16384  tile-major [b][t8][co64][j32]
constexpr size_t OFF_P      = 57344 + 16777216;   // 16*1024*64

// ---------------- pooling kernel: pooled[b,c] = mean_l relu(conv1(x)) ----------------
__global__ __launch_bounds__(256) void pool_kernel(const float* __restrict__ x,
    const float* __restrict__ c1w, const float* __restrict__ c1b, float* __restrict__ pooled)
{
    __shared__ float xbuf[2050];
    __shared__ float part[4][8];
    int b = blockIdx.x, tid = threadIdx.x;
    const float* xr = x + (size_t)b * L0;
    for (int i = tid; i < 2050; i += 256) xbuf[i] = (i >= 1 && i <= L0) ? xr[i - 1] : 0.f;
    __syncthreads();
    float w[24], bb[8];
#pragma unroll
    for (int i = 0; i < 24; i++) w[i] = c1w[i];
#pragma unroll
    for (int c = 0; c < 8; c++) bb[c] = c1b[c];
    float acc[8];
#pragma unroll
    for (int c = 0; c < 8; c++) acc[c] = 0.f;
    for (int l = tid; l < L0; l += 256) {
        float xm = xbuf[l], x0 = xbuf[l + 1], xp = xbuf[l + 2];
#pragma unroll
        for (int c = 0; c < 8; c++)
            acc[c] += fmaxf(fmaf(w[3 * c], xm, fmaf(w[3 * c + 1], x0, fmaf(w[3 * c + 2], xp, bb[c]))), 0.f);
    }
#pragma unroll
    for (int c = 0; c < 8; c++) {
#pragma unroll
        for (int off = 32; off > 0; off >>= 1)
            acc[c] += __shfl_down(acc[c], off, 64);
    }
    int wv = tid >> 6, ln = tid & 63;
    if (ln == 0) {
#pragma unroll
        for (int c = 0; c < 8; c++) part[wv][c] = acc[c];
    }
    __syncthreads();
    if (tid < 8) {
        float s = part[0][tid] + part[1][tid] + part[2][tid] + part[3][tid];
        pooled[b * 8 + tid] = s * (1.f / L0);
    }
}

// ---------------- weight repack + BN fold: wq[e][co][ci][4] ----------------
__global__ __launch_bounds__(256) void repack_kernel(
    const float* __restrict__ ew1, const float* __restrict__ eb1, const float* __restrict__ g1,
    const float* __restrict__ bb1, const float* __restrict__ m1, const float* __restrict__ v1,
    const float* __restrict__ ew2, const float* __restrict__ eb2, const float* __restrict__ g2,
    const float* __restrict__ bb2, const float* __restrict__ m2, const float* __restrict__ v2,
    const float* __restrict__ ew3, const float* __restrict__ eb3, const float* __restrict__ g3,
    const float* __restrict__ bb3, const float* __restrict__ m3, const float* __restrict__ v3,
    float* __restrict__ w1q, float* __restrict__ w2q, float* __restrict__ w3q,
    float* __restrict__ b1p, float* __restrict__ b2p, float* __restrict__ b3p)
{
    int i = blockIdx.x * 256 + threadIdx.x;
    if (i < 2048) {
        int k = i & 3, ci = (i >> 2) & 7, co = (i >> 5) & 15, e = i >> 9;
        int ec = e * 16 + co;
        float A = g1[ec] * rsqrtf(v1[ec] + 1e-5f);
        w1q[i] = (k < 3) ? ew1[(ec * 8 + ci) * 3 + k] * A : 0.f;
    } else if (i < 10240) {
        int ii = i - 2048;
        int k = ii & 3, ci = (ii >> 2) & 15, co = (ii >> 6) & 31, e = ii >> 11;
        int ec = e * 32 + co;
        float A = g2[ec] * rsqrtf(v2[ec] + 1e-5f);
        w2q[ii] = (k < 3) ? ew2[(ec * 16 + ci) * 3 + k] * A : 0.f;
    } else if (i < 43008) {
        int ii = i - 10240;
        int k = ii & 3, ci = (ii >> 2) & 31, co = (ii >> 7) & 63, e = ii >> 13;
        int ec = e * 64 + co;
        float A = g3[ec] * rsqrtf(v3[ec] + 1e-5f);
        w3q[ii] = (k < 3) ? ew3[(ec * 32 + ci) * 3 + k] * A : 0.f;
    } else if (i < 43456) {
        int j = i - 43008;
        if (j < 64)       { float A = g1[j] * rsqrtf(v1[j] + 1e-5f); b1p[j] = fmaf(eb1[j] - m1[j], A, bb1[j]); }
        else if (j < 192) { int q = j - 64;  float A = g2[q] * rsqrtf(v2[q] + 1e-5f); b2p[q] = fmaf(eb2[q] - m2[q], A, bb2[q]); }
        else              { int q = j - 192; float A = g3[q] * rsqrtf(v3[q] + 1e-5f); b3p[q] = fmaf(eb3[q] - m3[q], A, bb3[q]); }
    }
}

// ---------------- router: softmax, top-2, gates, aux loss ----------------
__global__ __launch_bounds__(1024) void router_kernel(const float* __restrict__ pooled,
    const float* __restrict__ rw, const float* __restrict__ rb,
    int* __restrict__ tidx, float* __restrict__ tg, float* __restrict__ aux)
{
    __shared__ float pr[4][1024];
    int b = threadIdx.x;
    float p[8];
#pragma unroll
    for (int c = 0; c < 8; c++) p[c] = pooled[b * 8 + c];
    float lg[4];
#pragma unroll
    for (int e = 0; e < 4; e++) {
        float a = rb[e];
#pragma unroll
        for (int c = 0; c < 8; c++) a = fmaf(p[c], rw[e * 8 + c], a);
        lg[e] = a;
    }
    float m = fmaxf(fmaxf(lg[0], lg[1]), fmaxf(lg[2], lg[3]));
    float pe[4]; float s = 0.f;
#pragma unroll
    for (int e = 0; e < 4; e++) { pe[e] = expf(lg[e] - m); s += pe[e]; }
    float inv = 1.f / s;
#pragma unroll
    for (int e = 0; e < 4; e++) pe[e] *= inv;
    int e0 = 0;
#pragma unroll
    for (int e = 1; e < 4; e++) if (pe[e] > pe[e0]) e0 = e;
    int e1 = -1;
#pragma unroll
    for (int e = 0; e < 4; e++) if (e != e0 && (e1 < 0 || pe[e] > pe[e1])) e1 = e;
    float s2 = pe[e0] + pe[e1];
    tidx[b * 2] = e0; tidx[b * 2 + 1] = e1;
    tg[b * 2] = pe[e0] / s2; tg[b * 2 + 1] = pe[e1] / s2;
#pragma unroll
    for (int e = 0; e < 4; e++) pr[e][b] = pe[e];
    __syncthreads();
    for (int off = 512; off > 0; off >>= 1) {
        if (b < off) {
#pragma unroll
            for (int e = 0; e < 4; e++) pr[e][b] += pr[e][b + off];
        }
        __syncthreads();
    }
    if (b == 0) {
        float mp[4]; float mm = 0.f;
#pragma unroll
        for (int e = 0; e < 4; e++) { mp[e] = pr[e][0] * (1.f / 1024.f); mm += mp[e]; }
        mm *= 0.25f;
        float var = 0.f;
#pragma unroll
        for (int e = 0; e < 4; e++) { float d = mp[e] - mm; var += d * d; }
        var *= (1.f / 3.f);
        float cv = sqrtf(var) / (mm + 1e-10f);
        aux[0] = cv * cv;
    }
}

// ---------------- expert chain, T=32 final positions per block (R5 structure) ----------------
constexpr int XB_OFF = 0;      // 284 (pad 288)
constexpr int E0_OFF = 288;    // 8 x 148
constexpr int O0_OFF = 1472;   // 8 x 148
constexpr int E1_OFF = 2656;   // 16 x 76
constexpr int O1_OFF = 3872;   // 16 x 76
constexpr int E2_OFF = 5088;   // 32 x 36
constexpr int O2_OFF = 6240;   // 32 x 36
constexpr int LDS_FLOATS = 7392;   // 29568 B -> 5 blocks/CU

// 1 output channel x 8 positions; weights per-channel-contiguous (immediate offsets)
template<int CI, int SIN>
__device__ __forceinline__ void conv1ch8(
    const float* __restrict__ wq,   // [CI][4] for this (e,co)
    const float bias,
    const float* __restrict__ Ein, const float* __restrict__ Oin,
    const int j0, float vE[8], float vO[8])
{
#pragma unroll
    for (int p = 0; p < 8; ++p) { vE[p] = bias; vO[p] = bias; }
#pragma unroll
    for (int ci = 0; ci < CI; ++ci) {
        const float4 w = *reinterpret_cast<const float4*>(wq + ci * 4);
        const float* ep = Ein + ci * SIN + j0;
        const float4 ea = *reinterpret_cast<const float4*>(ep);
        const float4 eb = *reinterpret_cast<const float4*>(ep + 4);
        const float e8 = ep[8];
        const float* op = Oin + ci * SIN + j0;
        const float4 oa = *reinterpret_cast<const float4*>(op);
        const float4 ob = *reinterpret_cast<const float4*>(op + 4);
        const float o8 = op[8];
        const float E[9] = {ea.x, ea.y, ea.z, ea.w, eb.x, eb.y, eb.z, eb.w, e8};
        const float O[9] = {oa.x, oa.y, oa.z, oa.w, ob.x, ob.y, ob.z, ob.w, o8};
#pragma unroll
        for (int p = 0; p < 8; ++p) {
            vE[p] = fmaf(w.x, E[p], fmaf(w.y, O[p], fmaf(w.z, E[p + 1], vE[p])));
            vO[p] = fmaf(w.x, O[p], fmaf(w.y, E[p + 1], fmaf(w.z, O[p + 1], vO[p])));
        }
    }
}

// pool+relu+guard, store to E/O split output
template<int SOUT, int LOUT, bool GUARDJ>
__device__ __forceinline__ void pool_store(
    const float vE[8], const float vO[8],
    float* __restrict__ Eout, float* __restrict__ Oout,
    const int co, const int j0, const int a_out, const int jmax)
{
    float v[8];
#pragma unroll
    for (int p = 0; p < 8; ++p) {
        int l = a_out + j0 + p;
        bool ok = (l >= 0) && (l < LOUT);
        if (GUARDJ) ok = ok && (j0 + p < jmax);
        v[p] = ok ? fmaxf(fmaxf(vE[p], vO[p]), 0.f) : 0.f;
    }
    *reinterpret_cast<float4*>(Eout + co * SOUT + (j0 >> 1)) = make_float4(v[0], v[2], v[4], v[6]);
    *reinterpret_cast<float4*>(Oout + co * SOUT + (j0 >> 1)) = make_float4(v[1], v[3], v[5], v[7]);
}

__global__ __launch_bounds__(256, 5) void expert_kernel(
    const float* __restrict__ x, const float* __restrict__ c1w, const float* __restrict__ c1b,
    const float* __restrict__ w1q, const float* __restrict__ w2q, const float* __restrict__ w3q,
    const float* __restrict__ b1p, const float* __restrict__ b2p, const float* __restrict__ b3p,
    const int* __restrict__ tidx, const float* __restrict__ tg,
    float* __restrict__ comb)
{
    __shared__ __align__(16) float lds[LDS_FLOATS];
    const int tid = threadIdx.x;
    const int bt = blockIdx.x;
    const int b = bt >> 3, t = bt & 7;
    const int a3 = t * 32, a2 = 2 * a3 - 1, a1 = 4 * a3 - 3, a0 = 8 * a3 - 7;
    const float* xr = x + (size_t)b * L0;
    float* xb = lds + XB_OFF;
    for (int m = tid; m < 284; m += 256) {
        int gpos = a0 - 1 + m;
        xb[m] = (gpos >= 0 && gpos < L0) ? xr[gpos] : 0.f;
    }
    __syncthreads();
    // stage0: conv1+relu -> E0/O0 (8 x 148), rel j in [0, 282)  [computed once]
    {
        const int ch = tid & 7;
        const int pj = tid >> 3;   // 0..31, parity fixed
        float wa = c1w[ch * 3], wb = c1w[ch * 3 + 1], wc = c1w[ch * 3 + 2], bc = c1b[ch];
        float* tgt = lds + ((pj & 1) ? O0_OFF : E0_OFF) + ch * 148;
        const int kb = pj >> 1;
        for (int k = 0; k < 9; ++k) {
            int j = pj + 32 * k;
            if (j >= 282) break;
            int l = a0 + j;
            float v = 0.f;
            if (l >= 0 && l < L0)
                v = fmaxf(fmaf(wa, xb[j], fmaf(wb, xb[j + 1], fmaf(wc, xb[j + 2], bc))), 0.f);
            tgt[kb + 16 * k] = v;
        }
    }
    const int ea = tidx[b * 2], eb2i = tidx[b * 2 + 1];
    const float ga = tg[b * 2], gb2 = tg[b * 2 + 1];
    // thread maps: tails confined to wave 0
    const int co1 = tid & 15, pg1 = tid >> 4;   // stage1: 16 ch x 16 pos-groups(8)
    const int co2 = tid & 31, pg2 = tid >> 5;   // stage2: 32 ch x 8 pos-groups(8)
    const int co3 = tid >> 2, pg3 = tid & 3;    // stage3: 64 ch x 4 pos-groups(8)
    const int j3 = 8 * pg3;
    float oacc[8];
#pragma unroll
    for (int p = 0; p < 8; p++) oacc[p] = 0.f;
    float vE[8], vO[8];
#pragma unroll 1
    for (int slot = 0; slot < 2; ++slot) {
        const int e = slot ? eb2i : ea;
        const float g = slot ? gb2 : ga;
        __syncthreads();   // E0/O0 ready (slot0) / prev-slot stage3 done reading E2
        // stage1: CI=8 CO=16, JOUT=138
        {
            const float* wq = w1q + (size_t)(e * 16 + co1) * 32;
            const float bias = b1p[e * 16 + co1];
            conv1ch8<8, 148>(wq, bias, lds + E0_OFF, lds + O0_OFF, 8 * pg1, vE, vO);
            pool_store<76, 1024, false>(vE, vO, lds + E1_OFF, lds + O1_OFF, co1, 8 * pg1, a1, 138);
            if (pg1 < 2) {
                int j0 = 128 + 8 * pg1;
                conv1ch8<8, 148>(wq, bias, lds + E0_OFF, lds + O0_OFF, j0, vE, vO);
                pool_store<76, 1024, true>(vE, vO, lds + E1_OFF, lds + O1_OFF, co1, j0, a1, 138);
            }
        }
        __syncthreads();
        // stage2: CI=16 CO=32, JOUT=66
        {
            const float* wq = w2q + (size_t)(e * 32 + co2) * 64;
            const float bias = b2p[e * 32 + co2];
            conv1ch8<16, 76>(wq, bias, lds + E1_OFF, lds + O1_OFF, 8 * pg2, vE, vO);
            pool_store<36, 512, false>(vE, vO, lds + E2_OFF, lds + O2_OFF, co2, 8 * pg2, a2, 66);
            if (pg2 == 0) {
                conv1ch8<16, 76>(wq, bias, lds + E1_OFF, lds + O1_OFF, 64, vE, vO);
                pool_store<36, 512, true>(vE, vO, lds + E2_OFF, lds + O2_OFF, co2, 64, a2, 66);
            }
        }
        __syncthreads();
        // stage3: CI=32 CO=64, JOUT=32 exact; gated accumulate in regs
        {
            const float* wq = w3q + (size_t)(e * 64 + co3) * 128;
            const float bias = b3p[e * 64 + co3];
            conv1ch8<32, 36>(wq, bias, lds + E2_OFF, lds + O2_OFF, j3, vE, vO);
#pragma unroll
            for (int p = 0; p < 8; ++p)
                oacc[p] = fmaf(g, fmaxf(fmaxf(vE[p], vO[p]), 0.f), oacc[p]);
        }
    }
    // tile-major comb: comb[b][t][co][j] -> block writes one contiguous 8KB burst
    float* cb = comb + (size_t)b * 16384 + (size_t)t * 2048 + co3 * 32 + j3;
    *reinterpret_cast<float4*>(cb)     = make_float4(oacc[0], oacc[1], oacc[2], oacc[3]);
    *reinterpret_cast<float4*>(cb + 4) = make_float4(oacc[4], oacc[5], oacc[6], oacc[7]);
}

// ---------------- fc1 split-K GEMM on tile-major comb: P[kc][b][64] ----------------
__global__ __launch_bounds__(256) void fc1_kernel(const float* __restrict__ comb,
    const float* __restrict__ w, float* __restrict__ P)
{
    __shared__ __align__(16) float at[64 * 65];
    __shared__ __align__(16) float wt[64 * 65];
    int bc = blockIdx.x;   // 0..15 row chunk
    int kc = blockIdx.y;   // 0..15 k chunk
    int tid = threadIdx.x;
    int tx = tid & 15, ty = tid >> 4;
    float acc[4][4];
#pragma unroll
    for (int i = 0; i < 4; i++)
#pragma unroll
        for (int j = 0; j < 4; j++) acc[i][j] = 0.f;
    int b0 = bc * 64;
    for (int kt = 0; kt < 16; ++kt) {
        int k0 = kc * 1024 + kt * 64;
        int co = k0 >> 8;        // flat k = co*256 + l, l = t*32 + j
        int l0 = k0 & 255;
        __syncthreads();
        for (int i = tid; i < 4096; i += 256) {
            int r = i >> 6, kk = i & 63;
            int l = l0 + kk;
            at[r * 65 + kk] = comb[(size_t)(b0 + r) * 16384 + ((l >> 5) << 11) + co * 32 + (l & 31)];
            wt[r * 65 + kk] = w[(size_t)r * 16384 + k0 + kk];
        }
        __syncthreads();
#pragma unroll 8
        for (int kk = 0; kk < 64; kk++) {
            float av[4], wv[4];
#pragma unroll
            for (int i = 0; i < 4; i++) av[i] = at[(ty * 4 + i) * 65 + kk];
#pragma unroll
            for (int j = 0; j < 4; j++) wv[j] = wt[(tx * 4 + j) * 65 + kk];
#pragma unroll
            for (int i = 0; i < 4; i++)
#pragma unroll
                for (int j = 0; j < 4; j++) acc[i][j] = fmaf(av[i], wv[j], acc[i][j]);
        }
    }
    float* Pp = P + (size_t)kc * 65536;
#pragma unroll
    for (int i = 0; i < 4; i++)
#pragma unroll
        for (int j = 0; j < 4; j++)
            Pp[(size_t)(b0 + ty * 4 + i) * 64 + tx * 4 + j] = acc[i][j];
}

// ---------------- reduce partials + bias + relu + fc2 ----------------
__global__ __launch_bounds__(64) void fc2_kernel(const float* __restrict__ P,
    const float* __restrict__ f1b, const float* __restrict__ w2, const float* __restrict__ b2,
    float* __restrict__ out)
{
    int b = blockIdx.x * 64 + threadIdx.x;  // 0..1023
    float z[64];
#pragma unroll
    for (int n = 0; n < 64; n++) z[n] = 0.f;
    for (int kc = 0; kc < 16; kc++) {
        const float* Pp = P + (size_t)kc * 65536 + (size_t)b * 64;
#pragma unroll
        for (int n = 0; n < 64; n++) z[n] += Pp[n];
    }
    float o[5] = {0.f, 0.f, 0.f, 0.f, 0.f};
#pragma unroll
    for (int n = 0; n < 64; n++) {
        float zz = fmaxf(z[n] + f1b[n], 0.f);
#pragma unroll
        for (int c = 0; c < 5; c++) o[c] = fmaf(zz, w2[c * 64 + n], o[c]);
    }
#pragma unroll
    for (int c = 0; c < 5; c++) out[b * 5 + c] = o[c] + b2[c];
}

extern "C" void kernel_launch(void* const* d_in, const int* in_sizes, int n_in,
                              void* d_out, int out_size, void* d_ws, size_t ws_size,
                              hipStream_t stream)
{
    const float* x   = (const float*)d_in[0];
    const float* c1w = (const float*)d_in[1];
    const float* c1b = (const float*)d_in[2];
    const float* ew1 = (const float*)d_in[3];
    const float* eb1 = (const float*)d_in[4];
    const float* g1  = (const float*)d_in[5];
    const float* bb1 = (const float*)d_in[6];
    const float* m1  = (const float*)d_in[7];
    const float* v1  = (const float*)d_in[8];
    const float* ew2 = (const float*)d_in[9];
    const float* eb2 = (const float*)d_in[10];
    const float* g2  = (const float*)d_in[11];
    const float* bb2 = (const float*)d_in[12];
    const float* m2  = (const float*)d_in[13];
    const float* v2  = (const float*)d_in[14];
    const float* ew3 = (const float*)d_in[15];
    const float* eb3 = (const float*)d_in[16];
    const float* g3  = (const float*)d_in[17];
    const float* bb3 = (const float*)d_in[18];
    const float* m3  = (const float*)d_in[19];
    const float* v3  = (const float*)d_in[20];
    const float* rw  = (const float*)d_in[21];
    const float* rb  = (const float*)d_in[22];
    const float* f1w = (const float*)d_in[23];
    const float* f1b = (const float*)d_in[24];
    const float* f2w = (const float*)d_in[25];
    const float* f2b = (const float*)d_in[26];

    float* ws     = (float*)d_ws;
    float* pooled = ws + OFF_POOLED;
    int*   tidx   = (int*)(ws + OFF_TOPKI);
    float* tg     = ws + OFF_TOPKG;
    float* b1p    = ws + OFF_B1;
    float* b2p    = ws + OFF_B2;
    float* b3p    = ws + OFF_B3;
    float* w1q    = ws + OFF_W1Q;
    float* w2q    = ws + OFF_W2Q;
    float* w3q    = ws + OFF_W3Q;
    float* comb   = ws + OFF_COMB;
    float* P      = ws + OFF_P;
    float* out    = (float*)d_out;

    hipLaunchKernelGGL(pool_kernel, dim3(1024), dim3(256), 0, stream, x, c1w, c1b, pooled);
    hipLaunchKernelGGL(repack_kernel, dim3(170), dim3(256), 0, stream,
                       ew1, eb1, g1, bb1, m1, v1, ew2, eb2, g2, bb2, m2, v2,
                       ew3, eb3, g3, bb3, m3, v3, w1q, w2q, w3q, b1p, b2p, b3p);
    hipLaunchKernelGGL(router_kernel, dim3(1), dim3(1024), 0, stream, pooled, rw, rb, tidx, tg, out + 5120);
    hipLaunchKernelGGL(expert_kernel, dim3(8192), dim3(256), 0, stream,
                       x, c1w, c1b, w1q, w2q, w3q, b1p, b2p, b3p, tidx, tg, comb);
    hipLaunchKernelGGL(fc1_kernel, dim3(16, 16), dim3(256), 0, stream, comb, f1w, P);
    hipLaunchKernelGGL(fc2_kernel, dim3(16), dim3(64), 0, stream, P, f1b, f2w, f2b, out);
}